// Round 5
// baseline (954.197 us; speedup 1.0000x reference)
//
#include <hip/hip_runtime.h>
#include <math.h>

#define N_NODES 100000
#define N_EDGES 1600000
#define DIM 32
#define N_GROUPS 64
#define BN_EPS 1e-5f

#define BIN_NODES 128
#define NBINS ((N_NODES + BIN_NODES - 1) / BIN_NODES)   // 782
#define EPB_HIST 8192
#define HIST_BLOCKS ((N_EDGES + EPB_HIST - 1) / EPB_HIST)  // 196

// ---- monotone float<->uint encoding for atomic max on floats ----
__device__ __forceinline__ unsigned enc_f32(float f) {
    unsigned u = __float_as_uint(f);
    return (u & 0x80000000u) ? ~u : (u | 0x80000000u);
}
__device__ __forceinline__ float dec_f32(unsigned u) {
    return (u & 0x80000000u) ? __uint_as_float(u & 0x7FFFFFFFu) : __uint_as_float(~u);
}

// Fold BN into weights: Wf[k][j] = W[k][j]*scale_j, shift_j = (b_j - mean_j)*scale_j + beta_j
__global__ void fold_kernel(const float* __restrict__ lin_W, const float* __restrict__ lin_b,
                            const float* __restrict__ lin_gamma, const float* __restrict__ lin_beta,
                            const float* __restrict__ lin_mean, const float* __restrict__ lin_var,
                            const float* __restrict__ conv_W, const float* __restrict__ conv_b,
                            const float* __restrict__ conv_gamma, const float* __restrict__ conv_beta,
                            const float* __restrict__ conv_mean, const float* __restrict__ conv_var,
                            float* __restrict__ Wf,   // [5][32][32]
                            float* __restrict__ shf)  // [5][32]
{
    int l = blockIdx.x;      // 0..2 = lin, 3..4 = conv
    int t = threadIdx.x;     // 0..1023
    const float *W, *b, *gm, *bt, *mn, *vr;
    if (l < 3) {
        W = lin_W + l * DIM * DIM; b = lin_b + l * DIM; gm = lin_gamma + l * DIM;
        bt = lin_beta + l * DIM;   mn = lin_mean + l * DIM; vr = lin_var + l * DIM;
    } else {
        int c = l - 3;
        W = conv_W + c * DIM * DIM; b = conv_b + c * DIM; gm = conv_gamma + c * DIM;
        bt = conv_beta + c * DIM;   mn = conv_mean + c * DIM; vr = conv_var + c * DIM;
    }
    int j = t & (DIM - 1);
    float scale = gm[j] / sqrtf(vr[j] + BN_EPS);
    Wf[l * DIM * DIM + t] = W[t] * scale;
    if (t < DIM) shf[l * DIM + t] = (b[t] - mn[t]) * scale + bt[t];
}

// ================= bin-grouped edge build (coarse CSR, 128-node bins) =================
// bincnt[b] = #edges with dst in bin b. LDS-staged to keep global atomic depth ~HIST_BLOCKS.
__global__ __launch_bounds__(256) void binhist_kernel(const int* __restrict__ dst,
                                                      int* __restrict__ bincnt) {
    __shared__ int cnt[NBINS];
    int t = threadIdx.x;
    for (int b = t; b < NBINS; b += 256) cnt[b] = 0;
    __syncthreads();
    int base = blockIdx.x * EPB_HIST;
    for (int i = 0; i < EPB_HIST / 256; ++i) {
        int e = base + i * 256 + t;
        if (e < N_EDGES) atomicAdd(&cnt[dst[e] >> 7], 1);
    }
    __syncthreads();
    for (int b = t; b < NBINS; b += 256)
        if (cnt[b] > 0) atomicAdd(&bincnt[b], cnt[b]);
}

// Exclusive scan of bincnt -> binoff (stable) and bincur (scatter cursor). One block.
__global__ __launch_bounds__(1024) void binscan_kernel(const int* __restrict__ bincnt,
                                                       int* __restrict__ binoff,
                                                       int* __restrict__ bincur) {
    __shared__ int s[1024];
    int t = threadIdx.x;
    int c = (t < NBINS) ? bincnt[t] : 0;
    s[t] = c;
    __syncthreads();
    for (int off = 1; off < 1024; off <<= 1) {
        int u = (t >= off) ? s[t - off] : 0;
        __syncthreads();
        s[t] += u;
        __syncthreads();
    }
    if (t < NBINS) { binoff[t] = s[t] - c; bincur[t] = s[t] - c; }
    if (t == 0) binoff[NBINS] = N_EDGES;
}

// Scatter packed edges (dstl<<17 | src) into bin-grouped binbuf.
// Two passes per 8192-edge chunk: LDS count -> per-(block,bin) global reservation ->
// LDS-cursor placement. Global atomic depth ~HIST_BLOCKS, writes are per-bin monotone runs.
__global__ __launch_bounds__(256) void binscatter_kernel(const int* __restrict__ src,
                                                         const int* __restrict__ dst,
                                                         int* __restrict__ bincur,
                                                         unsigned* __restrict__ binbuf) {
    __shared__ int cnt[NBINS];
    __shared__ int pos[NBINS];
    int t = threadIdx.x;
    for (int b = t; b < NBINS; b += 256) cnt[b] = 0;
    __syncthreads();
    int base = blockIdx.x * EPB_HIST;
    for (int i = 0; i < EPB_HIST / 256; ++i) {
        int e = base + i * 256 + t;
        if (e < N_EDGES) atomicAdd(&cnt[dst[e] >> 7], 1);
    }
    __syncthreads();
    for (int b = t; b < NBINS; b += 256) {
        int c = cnt[b];
        pos[b] = (c > 0) ? atomicAdd(&bincur[b], c) : 0;
    }
    __syncthreads();
    for (int i = 0; i < EPB_HIST / 256; ++i) {
        int e = base + i * 256 + t;
        if (e < N_EDGES) {
            int d = dst[e];
            int bin = d >> 7;
            int p = atomicAdd(&pos[bin], 1);
            binbuf[p] = ((unsigned)(d & 127) << 17) | (unsigned)src[e];
        }
    }
}

// ================= fused GIN layer: gather + conv-MLP + lin-MLP + pooling =============
// One block per 128-node bin. LDS accumulator for agg; conv output stays in LDS for lin.
__global__ __launch_bounds__(512) void gin_layer_kernel(
        const float* __restrict__ x,        // [N,32] layer input
        const unsigned* __restrict__ binbuf,
        const int* __restrict__ binoff,     // [NBINS+1]
        const float* __restrict__ Wc, const float* __restrict__ shc,   // conv folded
        const float* __restrict__ Wl, const float* __restrict__ shl,   // lin folded
        const int* __restrict__ batch,      // [N] sorted
        const float* __restrict__ lw_ptr,
        float* __restrict__ xout,           // [N,32] layer output (next x)
        float* __restrict__ Z,              // [N,32] accumulated
        unsigned* __restrict__ segmax)      // [G,32] encoded
{
    __shared__ float acc[BIN_NODES * DIM];   // 16 KB
    __shared__ float Wb[DIM * DIM];          // 4 KB
    __shared__ float shb[DIM];
    __shared__ unsigned estage[512];
    __shared__ unsigned segloc[8 * DIM];     // up to 8 consecutive groups per bin

    int t = threadIdx.x;
    int bin = blockIdx.x;
    int node0 = bin * BIN_NODES;
    int chan = t >> 5;       // 0..15
    int col = t & 31;

    for (int i = t; i < BIN_NODES * DIM; i += 512) acc[i] = 0.f;
    for (int i = t; i < DIM * DIM; i += 512) Wb[i] = Wc[i];
    if (t < DIM) shb[t] = shc[t];
    if (t < 8 * DIM) segloc[t] = 0;
    int beg = binoff[bin], end = binoff[bin + 1];
    __syncthreads();

    // ---- edge accumulation into LDS (ds_add; bank = col -> conflict-free/2-way) ----
    for (int r = beg; r < end; r += 512) {
        int cnt = end - r; if (cnt > 512) cnt = 512;
        if (t < cnt) estage[t] = binbuf[r + t];
        __syncthreads();
#pragma unroll 4
        for (int j = 0; j < 32; ++j) {
            int idx = chan + 16 * j;
            if (idx < cnt) {
                unsigned e = estage[idx];
                int s  = (int)(e & 0x1FFFFu);
                int dl = (int)(e >> 17);
                atomicAdd(&acc[dl * DIM + col], x[(size_t)s * DIM + col]);
            }
        }
        __syncthreads();
    }
    __syncthreads();

    float lw = lw_ptr[0];

    // ---- h = x + agg; x' = elu(h @ Wc + shc); write x' global, keep in LDS ----
    // Rows are channel-private per pass: in-wave LDS ordering makes the
    // add->read-row->overwrite sequence safe without barriers.
    for (int p = 0; p < BIN_NODES / 16; ++p) {
        int nl = p * 16 + chan;
        int node = node0 + nl;
        if (node < N_NODES) {
            acc[nl * DIM + col] += x[(size_t)node * DIM + col];
            float a = shb[col];
#pragma unroll
            for (int k = 0; k < DIM; ++k) a += acc[nl * DIM + k] * Wb[k * DIM + col];
            float hp = a > 0.f ? a : expm1f(a);
            xout[(size_t)node * DIM + col] = hp;
            acc[nl * DIM + col] = hp;
        }
    }
    __syncthreads();

    // ---- swap weights to lin ----
    for (int i = t; i < DIM * DIM; i += 512) Wb[i] = Wl[i];
    if (t < DIM) shb[t] = shl[t];
    int gfirst = batch[node0];
    __syncthreads();

    // ---- z = elu(x' @ Wl + shl); Z += lw*z; block-staged segment-max ----
    for (int p = 0; p < BIN_NODES / 16; ++p) {
        int nl = p * 16 + chan;
        int node = node0 + nl;
        if (node < N_NODES) {
            float a = shb[col];
#pragma unroll
            for (int k = 0; k < DIM; ++k) a += acc[nl * DIM + k] * Wb[k * DIM + col];
            float z = a > 0.f ? a : expm1f(a);
            float zw = lw * z;
            Z[(size_t)node * DIM + col] += zw;
            int g = batch[node];
            unsigned en = enc_f32(zw);
            int go = g - gfirst;
            if (go < 8) atomicMax(&segloc[go * DIM + col], en);
            else        atomicMax(&segmax[g * DIM + col], en);   // practically never
        }
    }
    __syncthreads();
    if (t < 8 * DIM) {
        unsigned v = segloc[t];
        if (v) atomicMax(&segmax[(gfirst + (t >> 5)) * DIM + (t & 31)], v);
    }
}

// ================= layer-0 lin MLP (input x0), hierarchical segment-max ===============
#define TILES_PER_BLOCK 16
__global__ __launch_bounds__(256) void lin_mlp_first_kernel(
        const float* __restrict__ h,       // [N,32]
        const float* __restrict__ Wf,      // [32,32] folded
        const float* __restrict__ shf,     // [32]
        const int* __restrict__ batch,     // [N] sorted
        const float* __restrict__ lw_ptr,
        float* __restrict__ Zout,          // [N,32]  (write, no read)
        unsigned* __restrict__ segmax)     // [G,32] encoded
{
    __shared__ float Wl[DIM * DIM];
    __shared__ float sh[DIM];
    __shared__ float hl[8 * DIM];
    int t = threadIdx.x;
    for (int i = t; i < DIM * DIM; i += 256) Wl[i] = Wf[i];
    if (t < DIM) sh[t] = shf[t];
    __syncthreads();

    int rl = t >> 5;
    int col = t & 31;
    float lw = lw_ptr[0];
    int row0 = blockIdx.x * (TILES_PER_BLOCK * 8);

    float m = 0.f;
    int gcur = -1;

    for (int tile = 0; tile < TILES_PER_BLOCK; ++tile) {
        int rbase = row0 + tile * 8;
        if (rbase >= N_NODES) break;
        int base = rbase * DIM;
        __syncthreads();
        hl[t] = h[base + t];
        __syncthreads();

        float acc = sh[col];
#pragma unroll
        for (int k = 0; k < DIM; ++k) acc += hl[rl * DIM + k] * Wl[k * DIM + col];
        float z = acc > 0.f ? acc : expm1f(acc);
        Zout[base + t] = lw * z;

        float segval = z;                  // layer 0 pools unweighted z
        int g = batch[rbase + rl];
        if (g != gcur) {
            if (gcur >= 0) atomicMax(&segmax[gcur * DIM + col], enc_f32(m));
            gcur = g;
            m = segval;
        } else {
            m = fmaxf(m, segval);
        }
    }
    if (gcur >= 0) atomicMax(&segmax[gcur * DIM + col], enc_f32(m));
}

// out[g][j] += decode(segmax[g][j])
__global__ void add_out_kernel(const unsigned* __restrict__ segmax, float* __restrict__ out) {
    int t = blockIdx.x * blockDim.x + threadIdx.x;  // 2048
    out[t] += dec_f32(segmax[t]);
}

extern "C" void kernel_launch(void* const* d_in, const int* in_sizes, int n_in,
                              void* d_out, int out_size, void* d_ws, size_t ws_size,
                              hipStream_t stream) {
    const float* x0        = (const float*)d_in[0];
    const int*   ei        = (const int*)d_in[1];     // (2,E): row0=src, row1=dst
    const int*   batch     = (const int*)d_in[2];
    const float* lw        = (const float*)d_in[3];
    const float* lin_W     = (const float*)d_in[4];
    const float* lin_b     = (const float*)d_in[5];
    const float* lin_gamma = (const float*)d_in[6];
    const float* lin_beta  = (const float*)d_in[7];
    const float* lin_mean  = (const float*)d_in[8];
    const float* lin_var   = (const float*)d_in[9];
    const float* conv_W    = (const float*)d_in[10];
    const float* conv_b    = (const float*)d_in[11];
    const float* conv_gamma= (const float*)d_in[12];
    const float* conv_beta = (const float*)d_in[13];
    const float* conv_mean = (const float*)d_in[14];
    const float* conv_var  = (const float*)d_in[15];

    float* out  = (float*)d_out;                 // [G*32]
    float* Z    = out + N_GROUPS * DIM;          // [N*32]
    float* xout = Z + (size_t)N_NODES * DIM;     // [N*32] final x

    char* p = (char*)d_ws;
    float*    xbuf   = (float*)p;    p += (size_t)N_NODES * DIM * sizeof(float);
    unsigned* binbuf = (unsigned*)p; p += (size_t)N_EDGES * sizeof(unsigned);
    int*      bincnt = (int*)p;      p += NBINS * sizeof(int);
    int*      binoff = (int*)p;      p += (NBINS + 1) * sizeof(int);
    int*      bincur = (int*)p;      p += NBINS * sizeof(int);
    unsigned* segmx  = (unsigned*)p; p += N_GROUPS * DIM * sizeof(unsigned);
    float*    Wf     = (float*)p;    p += 5 * DIM * DIM * sizeof(float);
    float*    shf    = (float*)p;    p += 5 * DIM * sizeof(float);

    const int* src = ei;
    const int* dst = ei + N_EDGES;

    const int linm_blocks = (N_NODES + TILES_PER_BLOCK * 8 - 1) / (TILES_PER_BLOCK * 8);

    hipMemsetAsync(out, 0, N_GROUPS * DIM * sizeof(float), stream);
    hipMemsetAsync(bincnt, 0, NBINS * sizeof(int), stream);
    fold_kernel<<<5, 1024, 0, stream>>>(lin_W, lin_b, lin_gamma, lin_beta, lin_mean, lin_var,
                                        conv_W, conv_b, conv_gamma, conv_beta, conv_mean, conv_var,
                                        Wf, shf);

    // ---- bin-grouped edge build (once, reused by both conv layers) ----
    binhist_kernel<<<HIST_BLOCKS, 256, 0, stream>>>(dst, bincnt);
    binscan_kernel<<<1, 1024, 0, stream>>>(bincnt, binoff, bincur);
    binscatter_kernel<<<HIST_BLOCKS, 256, 0, stream>>>(src, dst, bincur, binbuf);

    // ---- layer 0 ----
    hipMemsetAsync(segmx, 0, N_GROUPS * DIM * sizeof(unsigned), stream);
    lin_mlp_first_kernel<<<linm_blocks, 256, 0, stream>>>(x0, Wf, shf, batch, lw, Z, segmx);
    add_out_kernel<<<8, 256, 0, stream>>>(segmx, out);

    // ---- layer 1 (fused gather+conv+lin) ----
    hipMemsetAsync(segmx, 0, N_GROUPS * DIM * sizeof(unsigned), stream);
    gin_layer_kernel<<<NBINS, 512, 0, stream>>>(x0, binbuf, binoff,
                                                Wf + 3 * DIM * DIM, shf + 3 * DIM,
                                                Wf + 1 * DIM * DIM, shf + 1 * DIM,
                                                batch, lw + 1, xbuf, Z, segmx);
    add_out_kernel<<<8, 256, 0, stream>>>(segmx, out);

    // ---- layer 2 ----
    hipMemsetAsync(segmx, 0, N_GROUPS * DIM * sizeof(unsigned), stream);
    gin_layer_kernel<<<NBINS, 512, 0, stream>>>(xbuf, binbuf, binoff,
                                                Wf + 4 * DIM * DIM, shf + 4 * DIM,
                                                Wf + 2 * DIM * DIM, shf + 2 * DIM,
                                                batch, lw + 2, xout, Z, segmx);
    add_out_kernel<<<8, 256, 0, stream>>>(segmx, out);
}

// Round 6
// 396.482 us; speedup vs baseline: 2.4067x; 2.4067x over previous
//
#include <hip/hip_runtime.h>
#include <math.h>

#define N_NODES 100000
#define N_EDGES 1600000
#define DIM 32
#define N_GROUPS 64
#define BN_EPS 1e-5f

#define BIN_NODES 128
#define NBINS ((N_NODES + BIN_NODES - 1) / BIN_NODES)   // 782
#define EPB_HIST 8192
#define HIST_BLOCKS ((N_EDGES + EPB_HIST - 1) / EPB_HIST)  // 196

// ---- monotone float<->uint encoding for atomic max on floats ----
__device__ __forceinline__ unsigned enc_f32(float f) {
    unsigned u = __float_as_uint(f);
    return (u & 0x80000000u) ? ~u : (u | 0x80000000u);
}
__device__ __forceinline__ float dec_f32(unsigned u) {
    return (u & 0x80000000u) ? __uint_as_float(u & 0x7FFFFFFFu) : __uint_as_float(~u);
}

// Fold BN into weights: Wf[k][j] = W[k][j]*scale_j, shift_j = (b_j - mean_j)*scale_j + beta_j
__global__ void fold_kernel(const float* __restrict__ lin_W, const float* __restrict__ lin_b,
                            const float* __restrict__ lin_gamma, const float* __restrict__ lin_beta,
                            const float* __restrict__ lin_mean, const float* __restrict__ lin_var,
                            const float* __restrict__ conv_W, const float* __restrict__ conv_b,
                            const float* __restrict__ conv_gamma, const float* __restrict__ conv_beta,
                            const float* __restrict__ conv_mean, const float* __restrict__ conv_var,
                            float* __restrict__ Wf,   // [5][32][32]
                            float* __restrict__ shf)  // [5][32]
{
    int l = blockIdx.x;      // 0..2 = lin, 3..4 = conv
    int t = threadIdx.x;     // 0..1023
    const float *W, *b, *gm, *bt, *mn, *vr;
    if (l < 3) {
        W = lin_W + l * DIM * DIM; b = lin_b + l * DIM; gm = lin_gamma + l * DIM;
        bt = lin_beta + l * DIM;   mn = lin_mean + l * DIM; vr = lin_var + l * DIM;
    } else {
        int c = l - 3;
        W = conv_W + c * DIM * DIM; b = conv_b + c * DIM; gm = conv_gamma + c * DIM;
        bt = conv_beta + c * DIM;   mn = conv_mean + c * DIM; vr = conv_var + c * DIM;
    }
    int j = t & (DIM - 1);
    float scale = gm[j] / sqrtf(vr[j] + BN_EPS);
    Wf[l * DIM * DIM + t] = W[t] * scale;
    if (t < DIM) shf[l * DIM + t] = (b[t] - mn[t]) * scale + bt[t];
}

// ================= bin-grouped edge build (cheap, proven in R5) =================
__global__ __launch_bounds__(256) void binhist_kernel(const int* __restrict__ dst,
                                                      int* __restrict__ bincnt) {
    __shared__ int cnt[NBINS];
    int t = threadIdx.x;
    for (int b = t; b < NBINS; b += 256) cnt[b] = 0;
    __syncthreads();
    int base = blockIdx.x * EPB_HIST;
    for (int i = 0; i < EPB_HIST / 256; ++i) {
        int e = base + i * 256 + t;
        if (e < N_EDGES) atomicAdd(&cnt[dst[e] >> 7], 1);
    }
    __syncthreads();
    for (int b = t; b < NBINS; b += 256)
        if (cnt[b] > 0) atomicAdd(&bincnt[b], cnt[b]);
}

__global__ __launch_bounds__(1024) void binscan_kernel(const int* __restrict__ bincnt,
                                                       int* __restrict__ binoff,
                                                       int* __restrict__ bincur) {
    __shared__ int s[1024];
    int t = threadIdx.x;
    int c = (t < NBINS) ? bincnt[t] : 0;
    s[t] = c;
    __syncthreads();
    for (int off = 1; off < 1024; off <<= 1) {
        int u = (t >= off) ? s[t - off] : 0;
        __syncthreads();
        s[t] += u;
        __syncthreads();
    }
    if (t < NBINS) { binoff[t] = s[t] - c; bincur[t] = s[t] - c; }
    if (t == 0) binoff[NBINS] = N_EDGES;
}

// Scatter packed edges (dstl<<17 | src) into bin-grouped binbuf.
__global__ __launch_bounds__(256) void binscatter_kernel(const int* __restrict__ src,
                                                         const int* __restrict__ dst,
                                                         int* __restrict__ bincur,
                                                         unsigned* __restrict__ binbuf) {
    __shared__ int cnt[NBINS];
    __shared__ int pos[NBINS];
    int t = threadIdx.x;
    for (int b = t; b < NBINS; b += 256) cnt[b] = 0;
    __syncthreads();
    int base = blockIdx.x * EPB_HIST;
    for (int i = 0; i < EPB_HIST / 256; ++i) {
        int e = base + i * 256 + t;
        if (e < N_EDGES) atomicAdd(&cnt[dst[e] >> 7], 1);
    }
    __syncthreads();
    for (int b = t; b < NBINS; b += 256) {
        int c = cnt[b];
        pos[b] = (c > 0) ? atomicAdd(&bincur[b], c) : 0;
    }
    __syncthreads();
    for (int i = 0; i < EPB_HIST / 256; ++i) {
        int e = base + i * 256 + t;
        if (e < N_EDGES) {
            int d = dst[e];
            int bin = d >> 7;
            int p = atomicAdd(&pos[bin], 1);
            binbuf[p] = ((unsigned)(d & 127) << 17) | (unsigned)src[e];
        }
    }
}

// Counting sort within each bin -> exact per-node CSR (esrc grouped by node, nodeptr).
// One block per bin; writes are contiguous within the bin's segment (no amplification).
__global__ __launch_bounds__(256) void binsort_kernel(const unsigned* __restrict__ binbuf,
                                                      const int* __restrict__ binoff,
                                                      int* __restrict__ esrc,
                                                      int* __restrict__ nodeptr) {
    __shared__ int cnt[BIN_NODES];
    __shared__ int sc[BIN_NODES];
    int t = threadIdx.x;
    int bin = blockIdx.x;
    int beg = binoff[bin], end = binoff[bin + 1];
    if (t < BIN_NODES) cnt[t] = 0;
    __syncthreads();
    for (int e = beg + t; e < end; e += 256)
        atomicAdd(&cnt[binbuf[e] >> 17], 1);
    __syncthreads();
    int v = (t < BIN_NODES) ? cnt[t] : 0;
    if (t < BIN_NODES) sc[t] = v;
    __syncthreads();
    for (int off = 1; off < BIN_NODES; off <<= 1) {
        int u = (t < BIN_NODES && t >= off) ? sc[t - off] : 0;
        __syncthreads();
        if (t < BIN_NODES) sc[t] += u;
        __syncthreads();
    }
    if (t < BIN_NODES) {
        int excl = sc[t] - v;
        cnt[t] = excl;                          // reuse as cursor
        nodeptr[bin * BIN_NODES + t] = beg + excl;   // node >= N slots harmlessly = end
    }
    __syncthreads();
    for (int e = beg + t; e < end; e += 256) {
        unsigned pe = binbuf[e];
        int dl = (int)(pe >> 17);
        int p = atomicAdd(&cnt[dl], 1);
        esrc[beg + p] = (int)(pe & 0x1FFFFu);
    }
}

// ============== fused gather + conv-MLP: x'[i] = elu((x[i]+sum_j x[j]) @ Wc + shc) =====
// One wave per node (high parallelism); float4 gathers; h row via LDS; in-wave MLP.
__global__ __launch_bounds__(256) void gatherconv_kernel(
        const float* __restrict__ x,
        const int* __restrict__ esrc,
        const int* __restrict__ nodeptr,   // [>=N+1] monotone
        const float* __restrict__ Wc, const float* __restrict__ shc,
        float* __restrict__ xnext)
{
    __shared__ float Wb[DIM * DIM];
    __shared__ float shb[DIM];
    __shared__ float h[4][DIM];
    int t = threadIdx.x;
    for (int i = t; i < DIM * DIM; i += 256) Wb[i] = Wc[i];
    if (t < DIM) shb[t] = shc[t];
    __syncthreads();

    int wv = t >> 6;
    int lane = t & 63;
    int node = blockIdx.x * 4 + wv;          // grid exact: N/4
    int slot = lane >> 3;
    int c4 = (lane & 7) * 4;

    int beg = nodeptr[node];
    int end = nodeptr[node + 1];
    float4 acc = make_float4(0.f, 0.f, 0.f, 0.f);
    for (int e = beg + slot; e < end; e += 8) {
        int s = esrc[e];
        const float4 v = *(const float4*)(x + (size_t)s * DIM + c4);
        acc.x += v.x; acc.y += v.y; acc.z += v.z; acc.w += v.w;
    }
#pragma unroll
    for (int off = 8; off < 64; off <<= 1) {
        acc.x += __shfl_xor(acc.x, off, 64);
        acc.y += __shfl_xor(acc.y, off, 64);
        acc.z += __shfl_xor(acc.z, off, 64);
        acc.w += __shfl_xor(acc.w, off, 64);
    }
    if (slot == 0) {
        const float4 xv = *(const float4*)(x + (size_t)node * DIM + c4);
        float4 r = make_float4(acc.x + xv.x, acc.y + xv.y, acc.z + xv.z, acc.w + xv.w);
        *(float4*)(&h[wv][c4]) = r;          // same-wave LDS: no block barrier needed
    }
    // conv MLP: lanes 0-31 cols (k=0..15), lanes 32-63 same cols (k=16..31), then fold.
    int col = lane & 31;
    int half = lane >> 5;
    float a = 0.f;
#pragma unroll
    for (int k = 0; k < 16; ++k) {
        int kk = half * 16 + k;
        a += h[wv][kk] * Wb[kk * DIM + col];
    }
    a += __shfl_xor(a, 32, 64);
    if (half == 0) {
        a += shb[col];
        float hp = a > 0.f ? a : expm1f(a);
        xnext[(size_t)node * DIM + col] = hp;
    }
}

// ================= lin MLP + Z accumulate + hierarchical segment-max ===============
#define TILES_PER_BLOCK 16
template <bool FIRST>
__global__ __launch_bounds__(256) void lin_mlp_kernel(
        const float* __restrict__ h,       // [N,32]
        const float* __restrict__ Wf,      // [32,32] folded
        const float* __restrict__ shf,     // [32]
        const int* __restrict__ batch,     // [N] sorted
        const float* __restrict__ lw_ptr,
        float* __restrict__ Zout,          // [N,32]
        unsigned* __restrict__ segmax)     // [G,32] encoded
{
    __shared__ float Wl[DIM * DIM];
    __shared__ float sh[DIM];
    __shared__ float hl[8 * DIM];
    int t = threadIdx.x;
    for (int i = t; i < DIM * DIM; i += 256) Wl[i] = Wf[i];
    if (t < DIM) sh[t] = shf[t];
    __syncthreads();

    int rl = t >> 5;
    int col = t & 31;
    float lw = lw_ptr[0];
    int row0 = blockIdx.x * (TILES_PER_BLOCK * 8);

    float m = 0.f;
    int gcur = -1;

    for (int tile = 0; tile < TILES_PER_BLOCK; ++tile) {
        int rbase = row0 + tile * 8;
        if (rbase >= N_NODES) break;
        int base = rbase * DIM;
        __syncthreads();
        hl[t] = h[base + t];
        __syncthreads();

        float acc = sh[col];
#pragma unroll
        for (int k = 0; k < DIM; ++k) acc += hl[rl * DIM + k] * Wl[k * DIM + col];
        float z = acc > 0.f ? acc : expm1f(acc);
        float zw = lw * z;
        if (FIRST) Zout[base + t] = zw;
        else       Zout[base + t] += zw;

        float segval = FIRST ? z : zw;     // layer 0 pools unweighted z
        int g = batch[rbase + rl];
        if (g != gcur) {
            if (gcur >= 0) atomicMax(&segmax[gcur * DIM + col], enc_f32(m));
            gcur = g;
            m = segval;
        } else {
            m = fmaxf(m, segval);
        }
    }
    if (gcur >= 0) atomicMax(&segmax[gcur * DIM + col], enc_f32(m));
}

// out[g][j] += decode(segmax[g][j])
__global__ void add_out_kernel(const unsigned* __restrict__ segmax, float* __restrict__ out) {
    int t = blockIdx.x * blockDim.x + threadIdx.x;  // 2048
    out[t] += dec_f32(segmax[t]);
}

extern "C" void kernel_launch(void* const* d_in, const int* in_sizes, int n_in,
                              void* d_out, int out_size, void* d_ws, size_t ws_size,
                              hipStream_t stream) {
    const float* x0        = (const float*)d_in[0];
    const int*   ei        = (const int*)d_in[1];     // (2,E): row0=src, row1=dst
    const int*   batch     = (const int*)d_in[2];
    const float* lw        = (const float*)d_in[3];
    const float* lin_W     = (const float*)d_in[4];
    const float* lin_b     = (const float*)d_in[5];
    const float* lin_gamma = (const float*)d_in[6];
    const float* lin_beta  = (const float*)d_in[7];
    const float* lin_mean  = (const float*)d_in[8];
    const float* lin_var   = (const float*)d_in[9];
    const float* conv_W    = (const float*)d_in[10];
    const float* conv_b    = (const float*)d_in[11];
    const float* conv_gamma= (const float*)d_in[12];
    const float* conv_beta = (const float*)d_in[13];
    const float* conv_mean = (const float*)d_in[14];
    const float* conv_var  = (const float*)d_in[15];

    float* out  = (float*)d_out;                 // [G*32]
    float* Z    = out + N_GROUPS * DIM;          // [N*32]
    float* xout = Z + (size_t)N_NODES * DIM;     // [N*32] final x

    char* p = (char*)d_ws;
    float*    xbuf   = (float*)p;    p += (size_t)N_NODES * DIM * sizeof(float);
    unsigned* binbuf = (unsigned*)p; p += (size_t)N_EDGES * sizeof(unsigned);
    int*      esrc   = (int*)p;      p += (size_t)N_EDGES * sizeof(int);
    int*      nodeptr= (int*)p;      p += (NBINS * BIN_NODES + 1) * sizeof(int);
    int*      bincnt = (int*)p;      p += NBINS * sizeof(int);
    int*      binoff = (int*)p;      p += (NBINS + 1) * sizeof(int);
    int*      bincur = (int*)p;      p += NBINS * sizeof(int);
    unsigned* segmx  = (unsigned*)p; p += N_GROUPS * DIM * sizeof(unsigned);
    float*    Wf     = (float*)p;    p += 5 * DIM * DIM * sizeof(float);
    float*    shf    = (float*)p;    p += 5 * DIM * sizeof(float);

    const int* src = ei;
    const int* dst = ei + N_EDGES;

    const int linm_blocks = (N_NODES + TILES_PER_BLOCK * 8 - 1) / (TILES_PER_BLOCK * 8);
    const int gc_blocks   = N_NODES / 4;       // 25000

    hipMemsetAsync(out, 0, N_GROUPS * DIM * sizeof(float), stream);
    hipMemsetAsync(bincnt, 0, NBINS * sizeof(int), stream);
    fold_kernel<<<5, 1024, 0, stream>>>(lin_W, lin_b, lin_gamma, lin_beta, lin_mean, lin_var,
                                        conv_W, conv_b, conv_gamma, conv_beta, conv_mean, conv_var,
                                        Wf, shf);

    // ---- CSR build: bin-group then in-bin counting sort (reused by both layers) ----
    binhist_kernel<<<HIST_BLOCKS, 256, 0, stream>>>(dst, bincnt);
    binscan_kernel<<<1, 1024, 0, stream>>>(bincnt, binoff, bincur);
    binscatter_kernel<<<HIST_BLOCKS, 256, 0, stream>>>(src, dst, bincur, binbuf);
    binsort_kernel<<<NBINS, 256, 0, stream>>>(binbuf, binoff, esrc, nodeptr);

    // ---- layer 0 ----
    hipMemsetAsync(segmx, 0, N_GROUPS * DIM * sizeof(unsigned), stream);
    lin_mlp_kernel<true><<<linm_blocks, 256, 0, stream>>>(x0, Wf, shf, batch, lw, Z, segmx);
    add_out_kernel<<<8, 256, 0, stream>>>(segmx, out);

    // ---- layer 1 ----
    gatherconv_kernel<<<gc_blocks, 256, 0, stream>>>(x0, esrc, nodeptr,
                                                     Wf + 3 * DIM * DIM, shf + 3 * DIM, xbuf);
    hipMemsetAsync(segmx, 0, N_GROUPS * DIM * sizeof(unsigned), stream);
    lin_mlp_kernel<false><<<linm_blocks, 256, 0, stream>>>(xbuf, Wf + 1 * DIM * DIM, shf + 1 * DIM,
                                                           batch, lw + 1, Z, segmx);
    add_out_kernel<<<8, 256, 0, stream>>>(segmx, out);

    // ---- layer 2 ----
    gatherconv_kernel<<<gc_blocks, 256, 0, stream>>>(xbuf, esrc, nodeptr,
                                                     Wf + 4 * DIM * DIM, shf + 4 * DIM, xout);
    hipMemsetAsync(segmx, 0, N_GROUPS * DIM * sizeof(unsigned), stream);
    lin_mlp_kernel<false><<<linm_blocks, 256, 0, stream>>>(xout, Wf + 2 * DIM * DIM, shf + 2 * DIM,
                                                           batch, lw + 2, Z, segmx);
    add_out_kernel<<<8, 256, 0, stream>>>(segmx, out);
}